// Round 9
// baseline (425.925 us; speedup 1.0000x reference)
//
#include <hip/hip_runtime.h>
#include <hip/hip_bf16.h>
#include <hip/hip_cooperative_groups.h>

namespace cg = cooperative_groups;

namespace {

constexpr int B = 4;
constexpr int N = 8192;     // 2^13
constexpr int D = 16;
constexpr int R = 32;
constexpr int H = 64;
constexpr int E = 262144;   // 2^18

typedef __attribute__((ext_vector_type(8))) short short8;   // 8 x bf16 (4 VGPRs)
typedef __attribute__((ext_vector_type(4))) short short4v;  // 4 x bf16 (2 VGPRs)
typedef __attribute__((ext_vector_type(4))) float f32x4;    // MFMA accumulator

__device__ __forceinline__ float4 ld4(const float* p) {
    return *reinterpret_cast<const float4*>(p);
}
__device__ __forceinline__ float4 fma4(float a, float4 w, float4 c) {
    return float4{fmaf(a, w.x, c.x), fmaf(a, w.y, c.y),
                  fmaf(a, w.z, c.z), fmaf(a, w.w, c.w)};
}
__device__ __forceinline__ float4 relu4(float4 v) {
    return float4{fmaxf(v.x, 0.f), fmaxf(v.y, 0.f), fmaxf(v.z, 0.f), fmaxf(v.w, 0.f)};
}
__device__ __forceinline__ short bf16s(float f) {
    __hip_bfloat16 h = __float2bfloat16(f);   // RNE
    return __builtin_bit_cast(short, h);
}
__device__ __forceinline__ short8 pack8(float4 a, float4 b) {
    short8 o;
    o[0] = bf16s(a.x); o[1] = bf16s(a.y); o[2] = bf16s(a.z); o[3] = bf16s(a.w);
    o[4] = bf16s(b.x); o[5] = bf16s(b.y); o[6] = bf16s(b.z); o[7] = bf16s(b.w);
    return o;
}
// relu + pack 4 accumulator floats into 4 bf16 (one ds_write_b64)
__device__ __forceinline__ short4v pack4_relu(f32x4 c) {
    short4v o;
    o[0] = bf16s(fmaxf(c[0], 0.f)); o[1] = bf16s(fmaxf(c[1], 0.f));
    o[2] = bf16s(fmaxf(c[2], 0.f)); o[3] = bf16s(fmaxf(c[3], 0.f));
    return o;
}
// extract position i (0..31) from 4x int4 of packed bf16
__device__ __forceinline__ float red_get(const int4* uu, int i) {
    const int wsel = i >> 1;
    const int4 v = uu[wsel >> 2];
    const int word = (wsel & 3) == 0 ? v.x : (wsel & 3) == 1 ? v.y
                   : (wsel & 3) == 2 ? v.z : v.w;
    return (i & 1) ? __builtin_bit_cast(float, word & 0xffff0000)
                   : __builtin_bit_cast(float, (unsigned)word << 16);
}

constexpr int RED_S = 264;   // red stride in shorts; %8==0 keeps b128 reads 16B-aligned

__device__ __forceinline__ void prepack_w12(
    int t, const float* __restrict__ W1, const float* __restrict__ W2,
    short* __restrict__ w1p, short* __restrict__ w2p)
{
    // A/B-frag mapping (mfma_f32_16x16x32_bf16, verified m89):
    //   m|n = lane&15, k = (lane>>4)*8 + j  (identical for A and B)
    for (int i = t; i < 4 * 64 * 8; i += 256) {
        int j = i & 7, lane = (i >> 3) & 63, ct = i >> 9;
        int k = (lane >> 4) * 8 + j, n = ct * 16 + (lane & 15);
        w1p[i] = bf16s(W1[k * H + n]);
    }
    for (int i = t; i < 4 * 64 * 8; i += 256) {
        int j = i & 7, lane = (i >> 3) & 63, idx = i >> 9;
        int ct = idx >> 1, kc = idx & 1;
        int k = kc * 32 + (lane >> 4) * 8 + j, f = ct * 16 + (lane & 15);
        w2p[i] = bf16s(W2[k * R + f]);
    }
}
__device__ __forceinline__ void prepack_w34(
    int t, const float* __restrict__ W3, const float* __restrict__ W4,
    short* __restrict__ w3p, short* __restrict__ w4p)
{
    for (int i = t; i < 8 * 64 * 8; i += 256) {
        int j = i & 7, lane = (i >> 3) & 63, idx = i >> 9;
        int ct = idx >> 1, kc = idx & 1;
        int k = kc * 32 + (lane >> 4) * 8 + j, n = ct * 16 + (lane & 15);
        w3p[i] = (k < D + R) ? bf16s(W3[k * H + n]) : (short)0;
    }
    for (int i = t; i < 2 * 64 * 8; i += 256) {
        int j = i & 7, lane = (i >> 3) & 63, kc = i >> 9;
        int k = kc * 32 + (lane >> 4) * 8 + j, d = lane & 15;
        w4p[i] = bf16s(W4[k * D + d]);
    }
}

// ---------- cooperative sort pipeline @ 1024 blocks (4 blocks/CU) ----------
// phase0: zero rel/cnt + prepack -> hist -> scan (block 0) -> scatter
__global__ __launch_bounds__(256) void sort_coop_kernel(
    const int* __restrict__ senders, const int* __restrict__ receivers,
    const float* __restrict__ W1, const float* __restrict__ W2,
    const float* __restrict__ W3, const float* __restrict__ W4,
    int* __restrict__ cnt, int* __restrict__ pos, int2* __restrict__ sr,
    short* __restrict__ w1p, short* __restrict__ w2p,
    short* __restrict__ w3p, short* __restrict__ w4p,
    float4* __restrict__ relz)
{
    cg::grid_group grid = cg::this_grid();
    const int t = threadIdx.x;
    const int blk = blockIdx.x;

    // phase 0
    if (blk < 128) {
        const int base = blk * 256 + t;
        #pragma unroll
        for (int i = 0; i < 8; ++i)
            relz[base + i * 32768] = float4{0.f, 0.f, 0.f, 0.f};
    } else if (blk < 160) {
        cnt[(blk - 128) * 256 + t] = 0;
    } else if (blk == 160) {
        prepack_w12(t, W1, W2, w1p, w2p);
    } else if (blk == 161) {
        prepack_w34(t, W3, W4, w3p, w4p);
    }
    grid.sync();

    // phase 1: histogram, 1 edge/thread (1024*256 = E)
    const int e = blk * 256 + t;
    const int r = receivers[e];
    atomicAdd(cnt + r, 1);
    grid.sync();

    // phase 2: exclusive scan of 8192 bins (block 0; thread t owns bins [32t,32t+32))
    if (blk == 0) {
        __shared__ int wtot[4];
        int local[32];
        int s = 0;
        #pragma unroll
        for (int i = 0; i < 32; ++i) { local[i] = cnt[t * 32 + i]; s += local[i]; }
        int incl = s;
        const int lane = t & 63;
        #pragma unroll
        for (int d = 1; d < 64; d <<= 1) {
            int v = __shfl_up(incl, d, 64);
            if (lane >= d) incl += v;
        }
        if (lane == 63) wtot[t >> 6] = incl;
        __syncthreads();
        int base = incl - s;
        const int wv = t >> 6;
        #pragma unroll
        for (int i = 0; i < 4; ++i) base += (i < wv) ? wtot[i] : 0;
        #pragma unroll
        for (int i = 0; i < 32; ++i) { pos[t * 32 + i] = base; base += local[i]; }
    }
    grid.sync();

    // phase 3: scatter, 1 edge/thread
    const int p = atomicAdd(pos + r, 1);
    sr[p] = int2{senders[e], r};
}

// ---------- fallback sort pipeline (R6-proven multi-dispatch) ----------

__global__ __launch_bounds__(256) void hist_prepack_kernel(
    const int* __restrict__ receivers, int* __restrict__ cnt,
    const float* __restrict__ W1, const float* __restrict__ W2,
    const float* __restrict__ W3, const float* __restrict__ W4,
    short* __restrict__ w1p, short* __restrict__ w2p,
    short* __restrict__ w3p, short* __restrict__ w4p,
    float4* __restrict__ relz)
{
    if (blockIdx.x < 1024) {
        int e = blockIdx.x * 256 + threadIdx.x;
        atomicAdd(cnt + receivers[e], 1);
        return;
    }
    if (blockIdx.x >= 1025) {
        const int base = (blockIdx.x - 1025) * 256 + threadIdx.x;
        #pragma unroll
        for (int i = 0; i < 8; ++i)
            relz[base + i * 32768] = float4{0.f, 0.f, 0.f, 0.f};
        return;
    }
    prepack_w12(threadIdx.x, W1, W2, w1p, w2p);
    prepack_w34(threadIdx.x, W3, W4, w3p, w4p);
}

__global__ __launch_bounds__(1024) void scan_kernel(
    const int* __restrict__ cnt, int* __restrict__ pos)
{
    __shared__ int wtot[16];
    const int t = threadIdx.x;
    const int lane = t & 63;
    int local[8];
    int s = 0;
    #pragma unroll
    for (int i = 0; i < 8; ++i) { local[i] = cnt[t * 8 + i]; s += local[i]; }
    int incl = s;
    #pragma unroll
    for (int d = 1; d < 64; d <<= 1) {
        int v = __shfl_up(incl, d, 64);
        if (lane >= d) incl += v;
    }
    if (lane == 63) wtot[t >> 6] = incl;
    __syncthreads();
    int base = incl - s;
    const int wv = t >> 6;
    #pragma unroll
    for (int i = 0; i < 16; ++i) base += (i < wv) ? wtot[i] : 0;
    #pragma unroll
    for (int i = 0; i < 8; ++i) {
        pos[t * 8 + i] = base;
        base += local[i];
    }
}

__global__ __launch_bounds__(256) void scatter_kernel(
    const int* __restrict__ senders, const int* __restrict__ receivers,
    int* __restrict__ pos, int2* __restrict__ sr)
{
    int e = blockIdx.x * 256 + threadIdx.x;
    if (e < E) {
        int r = receivers[e];
        int p = atomicAdd(pos + r, 1);
        sr[p] = int2{senders[e], r};
    }
}

// ---------- MFMA edge MLP + segmented reduction (per-batch, 4096 blocks) ----------
// Block = 256 sorted positions in one batch; wave w owns 4 row-tiles of 16.
// Layer1: D1[hidden][edge] = W1^T(A) @ ein^T(B) -> hbuf (XOR-swizzled tile) b64
// Layer2: D2[edge][f]      = h(A) @ W2(B)       -> red (bf16) b64
__global__ __launch_bounds__(256, 3) void edge_mfma_kernel(
    const float* __restrict__ particles,
    const int2*  __restrict__ sr,
    const short* __restrict__ w1p, const float* __restrict__ b1,
    const short* __restrict__ w2p, const float* __restrict__ b2,
    float* __restrict__ rel)
{
    __shared__ short red[R * RED_S];          // [f][pos] bf16, stride 264 (16.9 KB)
    __shared__ short hbuf[4][16 * 72];        // per-wave [edge][hidden], stride 72
    __shared__ int   rs[256];

    const int tid  = threadIdx.x;
    const int lane = tid & 63;
    const int w    = tid >> 6;
    const int b    = blockIdx.x >> 10;        // 1024 blocks per batch
    const int p0   = (blockIdx.x & 1023) * 256;
    const int l15  = lane & 15;
    const int q    = lane >> 4;

    const int2 srv = sr[p0 + tid];
    rs[tid] = srv.y;

    // hoisted gather: distribute rows via shfl, issue all 8 dwordx4 loads up front
    float4 a0[4], a1[4];
    #pragma unroll
    for (int t = 0; t < 4; ++t) {
        int srow = __shfl(srv.x, t * 16 + l15);
        int rrow = __shfl(srv.y, t * 16 + l15);
        int row = (q < 2) ? srow : rrow;
        const float* src = particles + ((size_t)b * N + row) * D + (q & 1) * 8;
        a0[t] = ld4(src);
        a1[t] = ld4(src + 4);
    }

    // weight fragments (L2-hot, coalesced)
    short8 w1f[4], w2f[4];
    #pragma unroll
    for (int mt = 0; mt < 4; ++mt)
        w1f[mt] = *reinterpret_cast<const short8*>(w1p + (mt * 64 + lane) * 8);
    #pragma unroll
    for (int i = 0; i < 4; ++i)
        w2f[i] = *reinterpret_cast<const short8*>(w2p + (i * 64 + lane) * 8);

    // bias1: D1 rows = hidden = mt*16 + q*4 + rg
    f32x4 bias1[4];
    #pragma unroll
    for (int mt = 0; mt < 4; ++mt) {
        float4 t4 = ld4(b1 + mt * 16 + q * 4);
        bias1[mt] = f32x4{t4.x, t4.y, t4.z, t4.w};
    }
    // bias2: D2 cols = f = ct*16 + l15 (broadcast across the 4 row-regs)
    const float bias2a = b2[l15];
    const float bias2b = b2[16 + l15];

    short8 af[4];
    #pragma unroll
    for (int t = 0; t < 4; ++t) af[t] = pack8(a0[t], a1[t]);

    short* hb = &hbuf[w][0];

    #pragma unroll
    for (int t = 0; t < 4; ++t) {
        // layer1: 4 hidden m-tiles, K=32; C cols = edge, rows = hidden.
        // XOR-swizzle the tile slot by l15 to break the 4-way write aliasing.
        #pragma unroll
        for (int mt = 0; mt < 4; ++mt) {
            f32x4 c = bias1[mt];
            c = __builtin_amdgcn_mfma_f32_16x16x32_bf16(w1f[mt], af[t], c, 0, 0, 0);
            const int smt = (mt + l15) & 3;
            *reinterpret_cast<short4v*>(hb + l15 * 72 + smt * 16 + q * 4) = pack4_relu(c);
        }
        // read back A-frags of h: k = q*8+j; tile mt = k>>4, offset = k&15
        const int sm0 = ((q >> 1) + l15) & 3;
        const int sm1 = (2 + (q >> 1) + l15) & 3;
        short8 h0 = *reinterpret_cast<const short8*>(hb + l15 * 72 + sm0 * 16 + (q & 1) * 8);
        short8 h1 = *reinterpret_cast<const short8*>(hb + l15 * 72 + sm1 * 16 + (q & 1) * 8);

        // layer2: D2[edge][f], 2 f-tiles, K=64; C cols = f, rows = edge(pos)
        f32x4 r0 = {bias2a, bias2a, bias2a, bias2a};
        f32x4 r1 = {bias2b, bias2b, bias2b, bias2b};
        r0 = __builtin_amdgcn_mfma_f32_16x16x32_bf16(h0, w2f[0], r0, 0, 0, 0);
        r0 = __builtin_amdgcn_mfma_f32_16x16x32_bf16(h1, w2f[1], r0, 0, 0, 0);
        r1 = __builtin_amdgcn_mfma_f32_16x16x32_bf16(h0, w2f[2], r1, 0, 0, 0);
        r1 = __builtin_amdgcn_mfma_f32_16x16x32_bf16(h1, w2f[3], r1, 0, 0, 0);

        // relu + bf16-pack + stage: 4 consecutive positions at fixed f -> b64
        const int pb2 = w * 64 + t * 16 + q * 4;
        *reinterpret_cast<short4v*>(red + l15 * RED_S + pb2)        = pack4_relu(r0);
        *reinterpret_cast<short4v*>(red + (16 + l15) * RED_S + pb2) = pack4_relu(r1);
    }
    __syncthreads();

    // segmented reduction: group g handles positions [32g, 32g+32), lane = feature
    const int g = tid >> 5;
    const int f = tid & 31;
    const int base = g * 32;

    int4 uu[4];
    #pragma unroll
    for (int i = 0; i < 4; ++i)
        uu[i] = *reinterpret_cast<const int4*>(red + f * RED_S + base + 8 * i);
    int4 r4[8];
    #pragma unroll
    for (int i = 0; i < 8; ++i)
        r4[i] = *reinterpret_cast<const int4*>(rs + base + 4 * i);

    const int first = r4[0].x;
    const int last  = r4[7].w;
    if (first == last) {
        float acc = 0.f;
        #pragma unroll
        for (int i = 0; i < 32; ++i) acc += red_get(uu, i);
        atomicAdd(rel + ((size_t)b * N + first) * R + f, acc);
    } else {
        float acc = 0.f;
        int cur = first;
        #pragma unroll
        for (int i = 0; i < 32; ++i) {
            int rr = (i & 3) == 0 ? r4[i >> 2].x : (i & 3) == 1 ? r4[i >> 2].y
                   : (i & 3) == 2 ? r4[i >> 2].z : r4[i >> 2].w;
            float v = red_get(uu, i);
            if (rr != cur) {
                atomicAdd(rel + ((size_t)b * N + cur) * R + f, acc);
                acc = 0.f;
                cur = rr;
            }
            acc += v;
        }
        atomicAdd(rel + ((size_t)b * N + cur) * R + f, acc);
    }
}

// ---------- MFMA node MLP: one 16-node tile per wave ----------
__global__ __launch_bounds__(256, 4) void node_mfma_kernel(
    const float* __restrict__ particles,
    const float* __restrict__ rel,
    const short* __restrict__ w3p, const float* __restrict__ b3,
    const short* __restrict__ w4p, const float* __restrict__ b4,
    float* __restrict__ out)
{
    __shared__ short hbuf[4][16 * 72];

    const int tid  = threadIdx.x;
    const int lane = tid & 63;
    const int w    = tid >> 6;
    const int tile = blockIdx.x * 4 + w;        // [0, B*N/16)
    const int b    = tile >> 9;                 // 512 tiles per batch
    const int l15  = lane & 15;
    const int q    = lane >> 4;
    const int node = (tile & 511) * 16 + l15;

    const float* prow = particles + ((size_t)b * N + node) * D;
    const float* rrow = rel + ((size_t)b * N + node) * R;

    const float* src0 = (q < 2) ? (prow + (q & 1) * 8) : (rrow + (q & 1) * 8);
    float4 c0a = ld4(src0), c0b = ld4(src0 + 4);
    float4 c1a = {0.f, 0.f, 0.f, 0.f}, c1b = {0.f, 0.f, 0.f, 0.f};
    if (q < 2) { c1a = ld4(rrow + 16 + q * 8); c1b = ld4(rrow + 20 + q * 8); }

    short8 w3f[8], w4f[2];
    #pragma unroll
    for (int i = 0; i < 8; ++i)
        w3f[i] = *reinterpret_cast<const short8*>(w3p + (i * 64 + lane) * 8);
    #pragma unroll
    for (int i = 0; i < 2; ++i)
        w4f[i] = *reinterpret_cast<const short8*>(w4p + (i * 64 + lane) * 8);

    f32x4 bias3[4];
    #pragma unroll
    for (int mt = 0; mt < 4; ++mt) {
        float4 t4 = ld4(b3 + mt * 16 + q * 4);
        bias3[mt] = f32x4{t4.x, t4.y, t4.z, t4.w};
    }
    f32x4 bias4;
    { float4 t4 = ld4(b4 + q * 4); bias4 = f32x4{t4.x, t4.y, t4.z, t4.w}; }

    short8 a0 = pack8(c0a, c0b);
    short8 a1 = pack8(c1a, c1b);

    short* hb = &hbuf[w][0];
    #pragma unroll
    for (int mt = 0; mt < 4; ++mt) {
        f32x4 c = bias3[mt];
        c = __builtin_amdgcn_mfma_f32_16x16x32_bf16(w3f[mt * 2 + 0], a0, c, 0, 0, 0);
        c = __builtin_amdgcn_mfma_f32_16x16x32_bf16(w3f[mt * 2 + 1], a1, c, 0, 0, 0);
        *reinterpret_cast<short4v*>(hb + l15 * 72 + mt * 16 + q * 4) = pack4_relu(c);
    }
    short8 h0 = *reinterpret_cast<const short8*>(hb + l15 * 72 + q * 8);
    short8 h1 = *reinterpret_cast<const short8*>(hb + l15 * 72 + 32 + q * 8);

    f32x4 r = bias4;
    r = __builtin_amdgcn_mfma_f32_16x16x32_bf16(w4f[0], h0, r, 0, 0, 0);
    r = __builtin_amdgcn_mfma_f32_16x16x32_bf16(w4f[1], h1, r, 0, 0, 0);

    float4 pv = ld4(prow + q * 4);
    float4* po = reinterpret_cast<float4*>(out + ((size_t)b * N + node) * D + q * 4);
    *po = float4{pv.x + r[0], pv.y + r[1], pv.z + r[2], pv.w + r[3]};
}

// ---------- fallback path (fp32, correctness backstop) ----------

__global__ __launch_bounds__(256, 2) void edge_atomic_kernel(
    const float* __restrict__ particles,
    const int*   __restrict__ senders,
    const int*   __restrict__ receivers,
    const float* __restrict__ W1, const float* __restrict__ b1,
    const float* __restrict__ W2, const float* __restrict__ b2,
    float* __restrict__ rel)
{
    const int idx = blockIdx.x * 256 + threadIdx.x;
    const int b = idx >> 18;
    const int e = idx & (E - 1);
    const int s = senders[e];
    const int r = receivers[e];

    float4 ein4[8];
    {
        const float4* ps = reinterpret_cast<const float4*>(particles + ((size_t)b * N + s) * D);
        const float4* pr = reinterpret_cast<const float4*>(particles + ((size_t)b * N + r) * D);
        #pragma unroll
        for (int qq = 0; qq < 4; ++qq) ein4[qq] = ps[qq];
        #pragma unroll
        for (int qq = 0; qq < 4; ++qq) ein4[4 + qq] = pr[qq];
    }
    float4 rf4[8];
    #pragma unroll
    for (int qq = 0; qq < 8; ++qq) rf4[qq] = ld4(b2 + 4 * qq);

    for (int j4 = 0; j4 < H / 4; ++j4) {
        float4 h = ld4(b1 + 4 * j4);
        const float* w1c = W1 + 4 * j4;
        #pragma unroll
        for (int kv = 0; kv < 8; ++kv) {
            const float4 ev = ein4[kv];
            h = fma4(ev.x, ld4(w1c + (4 * kv + 0) * H), h);
            h = fma4(ev.y, ld4(w1c + (4 * kv + 1) * H), h);
            h = fma4(ev.z, ld4(w1c + (4 * kv + 2) * H), h);
            h = fma4(ev.w, ld4(w1c + (4 * kv + 3) * H), h);
        }
        h = relu4(h);
        const float* w2r = W2 + (4 * j4) * R;
        #pragma unroll
        for (int qq = 0; qq < 4; ++qq) {
            const float hq = (qq == 0) ? h.x : (qq == 1) ? h.y : (qq == 2) ? h.z : h.w;
            #pragma unroll
            for (int r4 = 0; r4 < 8; ++r4)
                rf4[r4] = fma4(hq, ld4(w2r + qq * R + 4 * r4), rf4[r4]);
        }
    }
    float* dst = rel + ((size_t)b * N + r) * R;
    #pragma unroll
    for (int r4 = 0; r4 < 8; ++r4) {
        float4 v = relu4(rf4[r4]);
        atomicAdd(dst + 4 * r4 + 0, v.x);
        atomicAdd(dst + 4 * r4 + 1, v.y);
        atomicAdd(dst + 4 * r4 + 2, v.z);
        atomicAdd(dst + 4 * r4 + 3, v.w);
    }
}

__global__ __launch_bounds__(256, 2) void node_valu_kernel(
    const float* __restrict__ particles,
    const float* __restrict__ rel,
    const float* __restrict__ W3, const float* __restrict__ b3,
    const float* __restrict__ W4, const float* __restrict__ b4,
    float* __restrict__ out)
{
    const int idx = blockIdx.x * 256 + threadIdx.x;
    float4 in4[12];
    {
        const float4* pp = reinterpret_cast<const float4*>(particles + (size_t)idx * D);
        #pragma unroll
        for (int qq = 0; qq < 4; ++qq) in4[qq] = pp[qq];
        const float4* pr = reinterpret_cast<const float4*>(rel + (size_t)idx * R);
        #pragma unroll
        for (int qq = 0; qq < 8; ++qq) in4[4 + qq] = pr[qq];
    }
    float4 dl4[4];
    #pragma unroll
    for (int qq = 0; qq < 4; ++qq) dl4[qq] = ld4(b4 + 4 * qq);

    for (int j4 = 0; j4 < H / 4; ++j4) {
        float4 h = ld4(b3 + 4 * j4);
        const float* w3c = W3 + 4 * j4;
        #pragma unroll
        for (int kv = 0; kv < 12; ++kv) {
            const float4 ev = in4[kv];
            h = fma4(ev.x, ld4(w3c + (4 * kv + 0) * H), h);
            h = fma4(ev.y, ld4(w3c + (4 * kv + 1) * H), h);
            h = fma4(ev.z, ld4(w3c + (4 * kv + 2) * H), h);
            h = fma4(ev.w, ld4(w3c + (4 * kv + 3) * H), h);
        }
        h = relu4(h);
        const float* w4r = W4 + (4 * j4) * D;
        #pragma unroll
        for (int qq = 0; qq < 4; ++qq) {
            const float hq = (qq == 0) ? h.x : (qq == 1) ? h.y : (qq == 2) ? h.z : h.w;
            #pragma unroll
            for (int d4 = 0; d4 < 4; ++d4)
                dl4[d4] = fma4(hq, ld4(w4r + qq * D + 4 * d4), dl4[d4]);
        }
    }
    float4* po = reinterpret_cast<float4*>(out + (size_t)idx * D);
    #pragma unroll
    for (int qq = 0; qq < 4; ++qq) {
        float4 v = dl4[qq];
        float4 pv = in4[qq];
        po[qq] = float4{pv.x + v.x, pv.y + v.y, pv.z + v.z, pv.w + v.w};
    }
}

}  // namespace

extern "C" void kernel_launch(void* const* d_in, const int* in_sizes, int n_in,
                              void* d_out, int out_size, void* d_ws, size_t ws_size,
                              hipStream_t stream) {
    const float* particles = (const float*)d_in[0];
    const int*   senders   = (const int*)d_in[1];
    const int*   receivers = (const int*)d_in[2];
    const float* W1 = (const float*)d_in[3];
    const float* b1 = (const float*)d_in[4];
    const float* W2 = (const float*)d_in[5];
    const float* b2 = (const float*)d_in[6];
    const float* W3 = (const float*)d_in[7];
    const float* b3 = (const float*)d_in[8];
    const float* W4 = (const float*)d_in[9];
    const float* b4 = (const float*)d_in[10];
    float* out = (float*)d_out;

    // workspace layout (256-B aligned slices)
    char* ws = (char*)d_ws;
    size_t off = 0;
    auto take = [&](size_t bytes) -> char* {
        char* p = ws + off;
        off = (off + bytes + 255) & ~(size_t)255;
        return p;
    };
    int*   cnt     = (int*)  take((size_t)N * 4);
    int*   pos     = (int*)  take((size_t)N * 4);
    int2*  sr      = (int2*) take((size_t)E * 8);
    float* rel     = (float*)take((size_t)B * N * R * 4);
    short* w1p     = (short*)take((size_t)4 * 64 * 8 * 2);
    short* w2p     = (short*)take((size_t)4 * 64 * 8 * 2);
    short* w3p     = (short*)take((size_t)8 * 64 * 8 * 2);
    short* w4p     = (short*)take((size_t)2 * 64 * 8 * 2);
    const bool fast = (off <= ws_size);

    if (fast) {
        float4* relz = (float4*)rel;
        void* cargs[] = {
            (void*)&senders, (void*)&receivers,
            (void*)&W1, (void*)&W2, (void*)&W3, (void*)&W4,
            (void*)&cnt, (void*)&pos, (void*)&sr,
            (void*)&w1p, (void*)&w2p, (void*)&w3p, (void*)&w4p,
            (void*)&relz
        };
        hipError_t ce = hipLaunchCooperativeKernel(
            (const void*)sort_coop_kernel, dim3(1024), dim3(256), cargs, 0, stream);
        if (ce != hipSuccess) {
            // fallback: R6-proven multi-dispatch sort pipeline
            hipMemsetAsync(cnt, 0, (size_t)N * 4, stream);
            hist_prepack_kernel<<<1153, 256, 0, stream>>>(
                receivers, cnt, W1, W2, W3, W4, w1p, w2p, w3p, w4p, relz);
            scan_kernel<<<1, 1024, 0, stream>>>(cnt, pos);
            scatter_kernel<<<E / 256, 256, 0, stream>>>(senders, receivers, pos, sr);
        }
        edge_mfma_kernel<<<(B * E) / 256, 256, 0, stream>>>(
            particles, sr, w1p, b1, w2p, b2, rel);
        node_mfma_kernel<<<(B * N / 16) / 4, 256, 0, stream>>>(
            particles, rel, w3p, b3, w4p, b4, out);
    } else {
        float* rel0 = (float*)d_ws;
        hipMemsetAsync(rel0, 0, (size_t)B * N * R * 4, stream);
        edge_atomic_kernel<<<(B * E) / 256, 256, 0, stream>>>(
            particles, senders, receivers, W1, b1, W2, b2, rel0);
        node_valu_kernel<<<(B * N) / 256, 256, 0, stream>>>(
            particles, rel0, W3, b3, W4, b4, out);
    }
}

// Round 10
// 137.298 us; speedup vs baseline: 3.1022x; 3.1022x over previous
//
#include <hip/hip_runtime.h>
#include <hip/hip_bf16.h>

namespace {

constexpr int B = 4;
constexpr int N = 8192;     // 2^13
constexpr int D = 16;
constexpr int R = 32;
constexpr int H = 64;
constexpr int E = 262144;   // 2^18

typedef __attribute__((ext_vector_type(8))) short short8;   // 8 x bf16 (4 VGPRs)
typedef __attribute__((ext_vector_type(4))) short short4v;  // 4 x bf16 (2 VGPRs)
typedef __attribute__((ext_vector_type(4))) float f32x4;    // MFMA accumulator

__device__ __forceinline__ float4 ld4(const float* p) {
    return *reinterpret_cast<const float4*>(p);
}
__device__ __forceinline__ float4 fma4(float a, float4 w, float4 c) {
    return float4{fmaf(a, w.x, c.x), fmaf(a, w.y, c.y),
                  fmaf(a, w.z, c.z), fmaf(a, w.w, c.w)};
}
__device__ __forceinline__ float4 relu4(float4 v) {
    return float4{fmaxf(v.x, 0.f), fmaxf(v.y, 0.f), fmaxf(v.z, 0.f), fmaxf(v.w, 0.f)};
}
__device__ __forceinline__ short bf16s(float f) {
    __hip_bfloat16 h = __float2bfloat16(f);   // RNE
    return __builtin_bit_cast(short, h);
}
__device__ __forceinline__ short8 pack8(float4 a, float4 b) {
    short8 o;
    o[0] = bf16s(a.x); o[1] = bf16s(a.y); o[2] = bf16s(a.z); o[3] = bf16s(a.w);
    o[4] = bf16s(b.x); o[5] = bf16s(b.y); o[6] = bf16s(b.z); o[7] = bf16s(b.w);
    return o;
}
// relu + pack 4 accumulator floats into 4 bf16 (one ds_write_b64)
__device__ __forceinline__ short4v pack4_relu(f32x4 c) {
    short4v o;
    o[0] = bf16s(fmaxf(c[0], 0.f)); o[1] = bf16s(fmaxf(c[1], 0.f));
    o[2] = bf16s(fmaxf(c[2], 0.f)); o[3] = bf16s(fmaxf(c[3], 0.f));
    return o;
}
// extract position i (0..31) from 4x int4 of packed bf16
__device__ __forceinline__ float red_get(const int4* uu, int i) {
    const int wsel = i >> 1;
    const int4 v = uu[wsel >> 2];
    const int word = (wsel & 3) == 0 ? v.x : (wsel & 3) == 1 ? v.y
                   : (wsel & 3) == 2 ? v.z : v.w;
    return (i & 1) ? __builtin_bit_cast(float, word & 0xffff0000)
                   : __builtin_bit_cast(float, (unsigned)word << 16);
}

constexpr int RED_S = 264;   // red stride in shorts; %8==0 keeps b128 reads 16B-aligned

__device__ __forceinline__ void prepack_w12(
    int t, const float* __restrict__ W1, const float* __restrict__ W2,
    short* __restrict__ w1p, short* __restrict__ w2p)
{
    // A/B-frag mapping (mfma_f32_16x16x32_bf16, verified m89):
    //   m|n = lane&15, k = (lane>>4)*8 + j  (identical for A and B)
    for (int i = t; i < 4 * 64 * 8; i += 256) {
        int j = i & 7, lane = (i >> 3) & 63, ct = i >> 9;
        int k = (lane >> 4) * 8 + j, n = ct * 16 + (lane & 15);
        w1p[i] = bf16s(W1[k * H + n]);
    }
    for (int i = t; i < 4 * 64 * 8; i += 256) {
        int j = i & 7, lane = (i >> 3) & 63, idx = i >> 9;
        int ct = idx >> 1, kc = idx & 1;
        int k = kc * 32 + (lane >> 4) * 8 + j, f = ct * 16 + (lane & 15);
        w2p[i] = bf16s(W2[k * R + f]);
    }
}
__device__ __forceinline__ void prepack_w34(
    int t, const float* __restrict__ W3, const float* __restrict__ W4,
    short* __restrict__ w3p, short* __restrict__ w4p)
{
    for (int i = t; i < 8 * 64 * 8; i += 256) {
        int j = i & 7, lane = (i >> 3) & 63, idx = i >> 9;
        int ct = idx >> 1, kc = idx & 1;
        int k = kc * 32 + (lane >> 4) * 8 + j, n = ct * 16 + (lane & 15);
        w3p[i] = (k < D + R) ? bf16s(W3[k * H + n]) : (short)0;
    }
    for (int i = t; i < 2 * 64 * 8; i += 256) {
        int j = i & 7, lane = (i >> 3) & 63, kc = i >> 9;
        int k = kc * 32 + (lane >> 4) * 8 + j, d = lane & 15;
        w4p[i] = bf16s(W4[k * D + d]);
    }
}

// ---------- sort pipeline (R6-proven multi-dispatch) ----------

__global__ __launch_bounds__(256) void hist_prepack_kernel(
    const int* __restrict__ receivers, int* __restrict__ cnt,
    const float* __restrict__ W1, const float* __restrict__ W2,
    const float* __restrict__ W3, const float* __restrict__ W4,
    short* __restrict__ w1p, short* __restrict__ w2p,
    short* __restrict__ w3p, short* __restrict__ w4p,
    float4* __restrict__ relz)
{
    if (blockIdx.x < 1024) {
        int e = blockIdx.x * 256 + threadIdx.x;
        atomicAdd(cnt + receivers[e], 1);
        return;
    }
    if (blockIdx.x >= 1025) {
        const int base = (blockIdx.x - 1025) * 256 + threadIdx.x;
        #pragma unroll
        for (int i = 0; i < 8; ++i)
            relz[base + i * 32768] = float4{0.f, 0.f, 0.f, 0.f};
        return;
    }
    prepack_w12(threadIdx.x, W1, W2, w1p, w2p);
    prepack_w34(threadIdx.x, W3, W4, w3p, w4p);
}

__global__ __launch_bounds__(1024) void scan_kernel(
    const int* __restrict__ cnt, int* __restrict__ pos)
{
    __shared__ int wtot[16];
    const int t = threadIdx.x;
    const int lane = t & 63;
    int local[8];
    int s = 0;
    #pragma unroll
    for (int i = 0; i < 8; ++i) { local[i] = cnt[t * 8 + i]; s += local[i]; }
    int incl = s;
    #pragma unroll
    for (int d = 1; d < 64; d <<= 1) {
        int v = __shfl_up(incl, d, 64);
        if (lane >= d) incl += v;
    }
    if (lane == 63) wtot[t >> 6] = incl;
    __syncthreads();
    int base = incl - s;
    const int wv = t >> 6;
    #pragma unroll
    for (int i = 0; i < 16; ++i) base += (i < wv) ? wtot[i] : 0;
    #pragma unroll
    for (int i = 0; i < 8; ++i) {
        pos[t * 8 + i] = base;
        base += local[i];
    }
}

__global__ __launch_bounds__(256) void scatter_kernel(
    const int* __restrict__ senders, const int* __restrict__ receivers,
    int* __restrict__ pos, int2* __restrict__ sr)
{
    int e = blockIdx.x * 256 + threadIdx.x;
    if (e < E) {
        int r = receivers[e];
        int p = atomicAdd(pos + r, 1);
        sr[p] = int2{senders[e], r};
    }
}

// ---------- MFMA edge MLP + segmented reduction (per-batch, 4096 blocks) ----------
// Block = 256 sorted positions in one batch; wave w owns 4 row-tiles of 16.
// Layer1: D1[hidden][edge] = W1^T(A) @ ein^T(B) -> hbuf via ds_write_b64,
//         tile slot XOR-swizzled by l15 to break 4-way write aliasing.
// Layer2: D2[edge][f]      = h(A) @ W2(B)       -> red (bf16) via ds_write_b64
__global__ __launch_bounds__(256, 4) void edge_mfma_kernel(
    const float* __restrict__ particles,
    const int2*  __restrict__ sr,
    const short* __restrict__ w1p, const float* __restrict__ b1,
    const short* __restrict__ w2p, const float* __restrict__ b2,
    float* __restrict__ rel)
{
    __shared__ short red[R * RED_S];          // [f][pos] bf16, stride 264 (16.9 KB)
    __shared__ short hbuf[4][16 * 72];        // per-wave [edge][hidden], stride 72
    __shared__ int   rs[256];

    const int tid  = threadIdx.x;
    const int lane = tid & 63;
    const int w    = tid >> 6;
    const int b    = blockIdx.x >> 10;        // 1024 blocks per batch
    const int p0   = (blockIdx.x & 1023) * 256;
    const int l15  = lane & 15;
    const int q    = lane >> 4;

    const int2 srv = sr[p0 + tid];
    rs[tid] = srv.y;

    // hoisted gather: distribute rows via shfl, issue all 8 dwordx4 loads up front
    float4 a0[4], a1[4];
    #pragma unroll
    for (int t = 0; t < 4; ++t) {
        int srow = __shfl(srv.x, t * 16 + l15);
        int rrow = __shfl(srv.y, t * 16 + l15);
        int row = (q < 2) ? srow : rrow;
        const float* src = particles + ((size_t)b * N + row) * D + (q & 1) * 8;
        a0[t] = ld4(src);
        a1[t] = ld4(src + 4);
    }

    // weight fragments (L2-hot, coalesced)
    short8 w1f[4], w2f[4];
    #pragma unroll
    for (int mt = 0; mt < 4; ++mt)
        w1f[mt] = *reinterpret_cast<const short8*>(w1p + (mt * 64 + lane) * 8);
    #pragma unroll
    for (int i = 0; i < 4; ++i)
        w2f[i] = *reinterpret_cast<const short8*>(w2p + (i * 64 + lane) * 8);

    // bias1: D1 rows = hidden = mt*16 + q*4 + rg
    f32x4 bias1[4];
    #pragma unroll
    for (int mt = 0; mt < 4; ++mt) {
        float4 t4 = ld4(b1 + mt * 16 + q * 4);
        bias1[mt] = f32x4{t4.x, t4.y, t4.z, t4.w};
    }
    // bias2: D2 cols = f = ct*16 + l15 (broadcast across the 4 row-regs)
    const float bias2a = b2[l15];
    const float bias2b = b2[16 + l15];

    short8 af[4];
    #pragma unroll
    for (int t = 0; t < 4; ++t) af[t] = pack8(a0[t], a1[t]);

    short* hb = &hbuf[w][0];

    #pragma unroll
    for (int t = 0; t < 4; ++t) {
        // layer1: 4 hidden m-tiles, K=32; C cols = edge, rows = hidden.
        // XOR-swizzle the tile slot by l15 (R9-verified) to break 4-way aliasing.
        #pragma unroll
        for (int mt = 0; mt < 4; ++mt) {
            f32x4 c = bias1[mt];
            c = __builtin_amdgcn_mfma_f32_16x16x32_bf16(w1f[mt], af[t], c, 0, 0, 0);
            const int smt = (mt + l15) & 3;
            *reinterpret_cast<short4v*>(hb + l15 * 72 + smt * 16 + q * 4) = pack4_relu(c);
        }
        // read back A-frags of h: k = q*8+j -> tile mt = k>>4 at slot (mt+l15)&3
        const int sm0 = ((q >> 1) + l15) & 3;
        const int sm1 = (2 + (q >> 1) + l15) & 3;
        short8 h0 = *reinterpret_cast<const short8*>(hb + l15 * 72 + sm0 * 16 + (q & 1) * 8);
        short8 h1 = *reinterpret_cast<const short8*>(hb + l15 * 72 + sm1 * 16 + (q & 1) * 8);

        // layer2: D2[edge][f], 2 f-tiles, K=64; C cols = f, rows = edge(pos)
        f32x4 r0 = {bias2a, bias2a, bias2a, bias2a};
        f32x4 r1 = {bias2b, bias2b, bias2b, bias2b};
        r0 = __builtin_amdgcn_mfma_f32_16x16x32_bf16(h0, w2f[0], r0, 0, 0, 0);
        r0 = __builtin_amdgcn_mfma_f32_16x16x32_bf16(h1, w2f[1], r0, 0, 0, 0);
        r1 = __builtin_amdgcn_mfma_f32_16x16x32_bf16(h0, w2f[2], r1, 0, 0, 0);
        r1 = __builtin_amdgcn_mfma_f32_16x16x32_bf16(h1, w2f[3], r1, 0, 0, 0);

        // relu + bf16-pack + stage: 4 consecutive positions at fixed f -> b64
        const int pb2 = w * 64 + t * 16 + q * 4;
        *reinterpret_cast<short4v*>(red + l15 * RED_S + pb2)        = pack4_relu(r0);
        *reinterpret_cast<short4v*>(red + (16 + l15) * RED_S + pb2) = pack4_relu(r1);
    }
    __syncthreads();

    // segmented reduction: group g handles positions [32g, 32g+32), lane = feature
    const int g = tid >> 5;
    const int f = tid & 31;
    const int base = g * 32;

    int4 uu[4];
    #pragma unroll
    for (int i = 0; i < 4; ++i)
        uu[i] = *reinterpret_cast<const int4*>(red + f * RED_S + base + 8 * i);
    int4 r4[8];
    #pragma unroll
    for (int i = 0; i < 8; ++i)
        r4[i] = *reinterpret_cast<const int4*>(rs + base + 4 * i);

    const int first = r4[0].x;
    const int last  = r4[7].w;
    if (first == last) {
        float acc = 0.f;
        #pragma unroll
        for (int i = 0; i < 32; ++i) acc += red_get(uu, i);
        atomicAdd(rel + ((size_t)b * N + first) * R + f, acc);
    } else {
        float acc = 0.f;
        int cur = first;
        #pragma unroll
        for (int i = 0; i < 32; ++i) {
            int rr = (i & 3) == 0 ? r4[i >> 2].x : (i & 3) == 1 ? r4[i >> 2].y
                   : (i & 3) == 2 ? r4[i >> 2].z : r4[i >> 2].w;
            float v = red_get(uu, i);
            if (rr != cur) {
                atomicAdd(rel + ((size_t)b * N + cur) * R + f, acc);
                acc = 0.f;
                cur = rr;
            }
            acc += v;
        }
        atomicAdd(rel + ((size_t)b * N + cur) * R + f, acc);
    }
}

// ---------- MFMA node MLP: one 16-node tile per wave ----------
__global__ __launch_bounds__(256, 4) void node_mfma_kernel(
    const float* __restrict__ particles,
    const float* __restrict__ rel,
    const short* __restrict__ w3p, const float* __restrict__ b3,
    const short* __restrict__ w4p, const float* __restrict__ b4,
    float* __restrict__ out)
{
    __shared__ short hbuf[4][16 * 72];

    const int tid  = threadIdx.x;
    const int lane = tid & 63;
    const int w    = tid >> 6;
    const int tile = blockIdx.x * 4 + w;        // [0, B*N/16)
    const int b    = tile >> 9;                 // 512 tiles per batch
    const int l15  = lane & 15;
    const int q    = lane >> 4;
    const int node = (tile & 511) * 16 + l15;

    const float* prow = particles + ((size_t)b * N + node) * D;
    const float* rrow = rel + ((size_t)b * N + node) * R;

    const float* src0 = (q < 2) ? (prow + (q & 1) * 8) : (rrow + (q & 1) * 8);
    float4 c0a = ld4(src0), c0b = ld4(src0 + 4);
    float4 c1a = {0.f, 0.f, 0.f, 0.f}, c1b = {0.f, 0.f, 0.f, 0.f};
    if (q < 2) { c1a = ld4(rrow + 16 + q * 8); c1b = ld4(rrow + 20 + q * 8); }

    short8 w3f[8], w4f[2];
    #pragma unroll
    for (int i = 0; i < 8; ++i)
        w3f[i] = *reinterpret_cast<const short8*>(w3p + (i * 64 + lane) * 8);
    #pragma unroll
    for (int i = 0; i < 2; ++i)
        w4f[i] = *reinterpret_cast<const short8*>(w4p + (i * 64 + lane) * 8);

    f32x4 bias3[4];
    #pragma unroll
    for (int mt = 0; mt < 4; ++mt) {
        float4 t4 = ld4(b3 + mt * 16 + q * 4);
        bias3[mt] = f32x4{t4.x, t4.y, t4.z, t4.w};
    }
    f32x4 bias4;
    { float4 t4 = ld4(b4 + q * 4); bias4 = f32x4{t4.x, t4.y, t4.z, t4.w}; }

    short8 a0 = pack8(c0a, c0b);
    short8 a1 = pack8(c1a, c1b);

    short* hb = &hbuf[w][0];
    #pragma unroll
    for (int mt = 0; mt < 4; ++mt) {
        f32x4 c = bias3[mt];
        c = __builtin_amdgcn_mfma_f32_16x16x32_bf16(w3f[mt * 2 + 0], a0, c, 0, 0, 0);
        c = __builtin_amdgcn_mfma_f32_16x16x32_bf16(w3f[mt * 2 + 1], a1, c, 0, 0, 0);
        *reinterpret_cast<short4v*>(hb + l15 * 72 + mt * 16 + q * 4) = pack4_relu(c);
    }
    short8 h0 = *reinterpret_cast<const short8*>(hb + l15 * 72 + q * 8);
    short8 h1 = *reinterpret_cast<const short8*>(hb + l15 * 72 + 32 + q * 8);

    f32x4 r = bias4;
    r = __builtin_amdgcn_mfma_f32_16x16x32_bf16(w4f[0], h0, r, 0, 0, 0);
    r = __builtin_amdgcn_mfma_f32_16x16x32_bf16(w4f[1], h1, r, 0, 0, 0);

    float4 pv = ld4(prow + q * 4);
    float4* po = reinterpret_cast<float4*>(out + ((size_t)b * N + node) * D + q * 4);
    *po = float4{pv.x + r[0], pv.y + r[1], pv.z + r[2], pv.w + r[3]};
}

// ---------- fallback path (fp32, correctness backstop) ----------

__global__ __launch_bounds__(256, 2) void edge_atomic_kernel(
    const float* __restrict__ particles,
    const int*   __restrict__ senders,
    const int*   __restrict__ receivers,
    const float* __restrict__ W1, const float* __restrict__ b1,
    const float* __restrict__ W2, const float* __restrict__ b2,
    float* __restrict__ rel)
{
    const int idx = blockIdx.x * 256 + threadIdx.x;
    const int b = idx >> 18;
    const int e = idx & (E - 1);
    const int s = senders[e];
    const int r = receivers[e];

    float4 ein4[8];
    {
        const float4* ps = reinterpret_cast<const float4*>(particles + ((size_t)b * N + s) * D);
        const float4* pr = reinterpret_cast<const float4*>(particles + ((size_t)b * N + r) * D);
        #pragma unroll
        for (int qq = 0; qq < 4; ++qq) ein4[qq] = ps[qq];
        #pragma unroll
        for (int qq = 0; qq < 4; ++qq) ein4[4 + qq] = pr[qq];
    }
    float4 rf4[8];
    #pragma unroll
    for (int qq = 0; qq < 8; ++qq) rf4[qq] = ld4(b2 + 4 * qq);

    for (int j4 = 0; j4 < H / 4; ++j4) {
        float4 h = ld4(b1 + 4 * j4);
        const float* w1c = W1 + 4 * j4;
        #pragma unroll
        for (int kv = 0; kv < 8; ++kv) {
            const float4 ev = ein4[kv];
            h = fma4(ev.x, ld4(w1c + (4 * kv + 0) * H), h);
            h = fma4(ev.y, ld4(w1c + (4 * kv + 1) * H), h);
            h = fma4(ev.z, ld4(w1c + (4 * kv + 2) * H), h);
            h = fma4(ev.w, ld4(w1c + (4 * kv + 3) * H), h);
        }
        h = relu4(h);
        const float* w2r = W2 + (4 * j4) * R;
        #pragma unroll
        for (int qq = 0; qq < 4; ++qq) {
            const float hq = (qq == 0) ? h.x : (qq == 1) ? h.y : (qq == 2) ? h.z : h.w;
            #pragma unroll
            for (int r4 = 0; r4 < 8; ++r4)
                rf4[r4] = fma4(hq, ld4(w2r + qq * R + 4 * r4), rf4[r4]);
        }
    }
    float* dst = rel + ((size_t)b * N + r) * R;
    #pragma unroll
    for (int r4 = 0; r4 < 8; ++r4) {
        float4 v = relu4(rf4[r4]);
        atomicAdd(dst + 4 * r4 + 0, v.x);
        atomicAdd(dst + 4 * r4 + 1, v.y);
        atomicAdd(dst + 4 * r4 + 2, v.z);
        atomicAdd(dst + 4 * r4 + 3, v.w);
    }
}

__global__ __launch_bounds__(256, 2) void node_valu_kernel(
    const float* __restrict__ particles,
    const float* __restrict__ rel,
    const float* __restrict__ W3, const float* __restrict__ b3,
    const float* __restrict__ W4, const float* __restrict__ b4,
    float* __restrict__ out)
{
    const int idx = blockIdx.x * 256 + threadIdx.x;
    float4 in4[12];
    {
        const float4* pp = reinterpret_cast<const float4*>(particles + (size_t)idx * D);
        #pragma unroll
        for (int qq = 0; qq < 4; ++qq) in4[qq] = pp[qq];
        const float4* pr = reinterpret_cast<const float4*>(rel + (size_t)idx * R);
        #pragma unroll
        for (int qq = 0; qq < 8; ++qq) in4[4 + qq] = pr[qq];
    }
    float4 dl4[4];
    #pragma unroll
    for (int qq = 0; qq < 4; ++qq) dl4[qq] = ld4(b4 + 4 * qq);

    for (int j4 = 0; j4 < H / 4; ++j4) {
        float4 h = ld4(b3 + 4 * j4);
        const float* w3c = W3 + 4 * j4;
        #pragma unroll
        for (int kv = 0; kv < 12; ++kv) {
            const float4 ev = in4[kv];
            h = fma4(ev.x, ld4(w3c + (4 * kv + 0) * H), h);
            h = fma4(ev.y, ld4(w3c + (4 * kv + 1) * H), h);
            h = fma4(ev.z, ld4(w3c + (4 * kv + 2) * H), h);
            h = fma4(ev.w, ld4(w3c + (4 * kv + 3) * H), h);
        }
        h = relu4(h);
        const float* w4r = W4 + (4 * j4) * D;
        #pragma unroll
        for (int qq = 0; qq < 4; ++qq) {
            const float hq = (qq == 0) ? h.x : (qq == 1) ? h.y : (qq == 2) ? h.z : h.w;
            #pragma unroll
            for (int d4 = 0; d4 < 4; ++d4)
                dl4[d4] = fma4(hq, ld4(w4r + qq * D + 4 * d4), dl4[d4]);
        }
    }
    float4* po = reinterpret_cast<float4*>(out + (size_t)idx * D);
    #pragma unroll
    for (int qq = 0; qq < 4; ++qq) {
        float4 v = dl4[qq];
        float4 pv = in4[qq];
        po[qq] = float4{pv.x + v.x, pv.y + v.y, pv.z + v.z, pv.w + v.w};
    }
}

}  // namespace

extern "C" void kernel_launch(void* const* d_in, const int* in_sizes, int n_in,
                              void* d_out, int out_size, void* d_ws, size_t ws_size,
                              hipStream_t stream) {
    const float* particles = (const float*)d_in[0];
    const int*   senders   = (const int*)d_in[1];
    const int*   receivers = (const int*)d_in[2];
    const float* W1 = (const float*)d_in[3];
    const float* b1 = (const float*)d_in[4];
    const float* W2 = (const float*)d_in[5];
    const float* b2 = (const float*)d_in[6];
    const float* W3 = (const float*)d_in[7];
    const float* b3 = (const float*)d_in[8];
    const float* W4 = (const float*)d_in[9];
    const float* b4 = (const float*)d_in[10];
    float* out = (float*)d_out;

    // workspace layout (256-B aligned slices)
    char* ws = (char*)d_ws;
    size_t off = 0;
    auto take = [&](size_t bytes) -> char* {
        char* p = ws + off;
        off = (off + bytes + 255) & ~(size_t)255;
        return p;
    };
    int*   cnt     = (int*)  take((size_t)N * 4);
    int*   pos     = (int*)  take((size_t)N * 4);
    int2*  sr      = (int2*) take((size_t)E * 8);
    float* rel     = (float*)take((size_t)B * N * R * 4);
    short* w1p     = (short*)take((size_t)4 * 64 * 8 * 2);
    short* w2p     = (short*)take((size_t)4 * 64 * 8 * 2);
    short* w3p     = (short*)take((size_t)8 * 64 * 8 * 2);
    short* w4p     = (short*)take((size_t)2 * 64 * 8 * 2);
    const bool fast = (off <= ws_size);

    if (fast) {
        hipMemsetAsync(cnt, 0, (size_t)N * 4, stream);
        hist_prepack_kernel<<<1153, 256, 0, stream>>>(
            receivers, cnt, W1, W2, W3, W4, w1p, w2p, w3p, w4p, (float4*)rel);
        scan_kernel<<<1, 1024, 0, stream>>>(cnt, pos);
        scatter_kernel<<<E / 256, 256, 0, stream>>>(senders, receivers, pos, sr);
        edge_mfma_kernel<<<(B * E) / 256, 256, 0, stream>>>(
            particles, sr, w1p, b1, w2p, b2, rel);
        node_mfma_kernel<<<(B * N / 16) / 4, 256, 0, stream>>>(
            particles, rel, w3p, b3, w4p, b4, out);
    } else {
        float* rel0 = (float*)d_ws;
        hipMemsetAsync(rel0, 0, (size_t)B * N * R * 4, stream);
        edge_atomic_kernel<<<(B * E) / 256, 256, 0, stream>>>(
            particles, senders, receivers, W1, b1, W2, b2, rel0);
        node_valu_kernel<<<(B * N) / 256, 256, 0, stream>>>(
            particles, rel0, W3, b3, W4, b4, out);
    }
}